// Round 2
// baseline (433.543 us; speedup 1.0000x reference)
//
#include <hip/hip_runtime.h>

// MS-SSIM loss, 5 levels, fused per-level kernel.
// Tile: 64 (cols) x 16 (rows) per 256-thread block; LDS = 35.8 KB -> 4 blocks/CU.
// Phase H: horizontal 11-tap Gaussian of {x,y,xx,yy,xy}; r-major lane mapping
//          (conflict-free transposed LDS writes, pitch 28); interior blocks use
//          aligned float4 window loads, boundary blocks masked scalar loads.
// Phase V: contiguous ds_read_b128 (uniform banks), vertical conv in regs,
//          fused SSIM (v_rcp), wave reduce, one atomicAdd per block.
// Avg-pool 2x2 for the next level fused (one output per thread, float2 loads).

#define TW 64
#define TH 16
#define HHALO 26            // TH + 10
#define HPITCH 28           // halo padded to multiple of 4 (16B-aligned b128)
#define PLANE (TW * HPITCH) // 1792 floats per field plane
#define NIMG 48             // 16 * 3

__global__ __launch_bounds__(256, 4) void ssim_level_kernel(
    const float* __restrict__ x, const float* __restrict__ y,
    float* __restrict__ dsx, float* __restrict__ dsy,
    float* __restrict__ sum_out, int H, int W, int do_ds)
{
    const float G[11] = {
        0.00102839f, 0.00759877f, 0.03600077f, 0.10936069f, 0.21300539f,
        0.26601173f, 0.21300539f, 0.10936069f, 0.03600077f, 0.00759877f,
        0.00102839f};
    const float C1 = 4.0e-4f;
    const float C2 = 3.6e-3f;

    __shared__ __align__(16) float hfT[5 * PLANE]; // 35,840 B
    __shared__ float wred[4];

    const int t   = threadIdx.x;
    const int img = blockIdx.z;
    const int C0  = blockIdx.x * TW;
    const int R0  = blockIdx.y * TH;
    const long base = (long)img * H * W;

    // ---- fused avg-pool 2x2 for next level: exactly one output per thread ----
    if (do_ds) {
        const int dsW = W >> 1, dsH = H >> 1;
        const long dbase = (long)img * dsH * dsW;
        const int dr = t >> 5;       // 0..7
        const int dc = t & 31;       // 0..31
        const int gr2 = (R0 >> 1) + dr;
        const int gc2 = (C0 >> 1) + dc;
        if (gr2 < dsH && gc2 < dsW) {
            const long src = base + (long)(2 * gr2) * W + 2 * gc2;
            const float2 a0 = *reinterpret_cast<const float2*>(x + src);
            const float2 a1 = *reinterpret_cast<const float2*>(x + src + W);
            const float2 b0 = *reinterpret_cast<const float2*>(y + src);
            const float2 b1 = *reinterpret_cast<const float2*>(y + src + W);
            dsx[dbase + (long)gr2 * dsW + gc2] = 0.25f * (a0.x + a0.y + a1.x + a1.y);
            dsy[dbase + (long)gr2 * dsW + gc2] = 0.25f * (b0.x + b0.y + b1.x + b1.y);
        }
    }

    // column-interior fast path? window is [C0+c0-8, C0+c0+12), c0 max = 60
    const bool colFast = (C0 >= 8) && (C0 + TW + 8 <= W);

    // ---- Phase H: 26 halo rows x 16 col-quads = 416 strips, r-major lanes ----
    for (int s = t; s < HHALO * (TW / 4); s += 256) {
        const int r  = s % HHALO;        // consecutive lanes -> consecutive r
        const int q  = s / HHALO;
        const int c0 = q << 2;
        const int gr = R0 + r - 5;
        const bool rok = ((unsigned)gr < (unsigned)H);

        float xv[20], yv[20];
        if (colFast) {
            if (rok) {
                const float* px = x + base + (long)gr * W + (C0 + c0 - 8);
                const float* py = y + base + (long)gr * W + (C0 + c0 - 8);
#pragma unroll
                for (int v = 0; v < 5; ++v) {
                    const float4 a = reinterpret_cast<const float4*>(px)[v];
                    const float4 b = reinterpret_cast<const float4*>(py)[v];
                    xv[4 * v + 0] = a.x; xv[4 * v + 1] = a.y;
                    xv[4 * v + 2] = a.z; xv[4 * v + 3] = a.w;
                    yv[4 * v + 0] = b.x; yv[4 * v + 1] = b.y;
                    yv[4 * v + 2] = b.z; yv[4 * v + 3] = b.w;
                }
            } else {
#pragma unroll
                for (int k = 0; k < 20; ++k) { xv[k] = 0.f; yv[k] = 0.f; }
            }
        } else {
            const float* xrow = x + base + (long)gr * W;
            const float* yrow = y + base + (long)gr * W;
#pragma unroll
            for (int k = 0; k < 20; ++k) { xv[k] = 0.f; yv[k] = 0.f; }
#pragma unroll
            for (int k = 0; k < 14; ++k) {   // only indices 3..16 are consumed
                const int gc = C0 + c0 + k - 5;
                const bool ok = rok && ((unsigned)gc < (unsigned)W);
                if (ok) { xv[k + 3] = xrow[gc]; yv[k + 3] = yrow[gc]; }
            }
        }

        float xx[14], yy[14], xy[14];
#pragma unroll
        for (int k = 0; k < 14; ++k) {
            const float a = xv[k + 3], b = yv[k + 3];
            xx[k] = a * a; yy[k] = b * b; xy[k] = a * b;
        }

#pragma unroll
        for (int j = 0; j < 4; ++j) {
            float hx = 0.f, hy = 0.f, hxx = 0.f, hyy = 0.f, hxy = 0.f;
#pragma unroll
            for (int k = 0; k < 11; ++k) {
                const float g = G[k];
                hx  = fmaf(g, xv[j + k + 3], hx);
                hy  = fmaf(g, yv[j + k + 3], hy);
                hxx = fmaf(g, xx[j + k], hxx);
                hyy = fmaf(g, yy[j + k], hyy);
                hxy = fmaf(g, xy[j + k], hxy);
            }
            float* hp = &hfT[(c0 + j) * HPITCH + r];
            hp[0 * PLANE] = hx;
            hp[1 * PLANE] = hy;
            hp[2 * PLANE] = hxx;
            hp[3 * PLANE] = hyy;
            hp[4 * PLANE] = hxy;
        }
    }
    __syncthreads();

    // ---- Phase V: thread = (col, 4-row strip); 64 x 4 = 256 strips ----
    const int c  = t & 63;
    const int r0 = (t >> 6) << 2;
    float acc[5][4];
#pragma unroll
    for (int f = 0; f < 5; ++f) {
        const float* hp = &hfT[f * PLANE + c * HPITCH + r0];
        float hv[14];
        const float4 a0 = *reinterpret_cast<const float4*>(hp);
        const float4 a1 = *reinterpret_cast<const float4*>(hp + 4);
        const float4 a2 = *reinterpret_cast<const float4*>(hp + 8);
        const float2 a3 = *reinterpret_cast<const float2*>(hp + 12);
        hv[0] = a0.x;  hv[1] = a0.y;  hv[2] = a0.z;  hv[3] = a0.w;
        hv[4] = a1.x;  hv[5] = a1.y;  hv[6] = a1.z;  hv[7] = a1.w;
        hv[8] = a2.x;  hv[9] = a2.y;  hv[10] = a2.z; hv[11] = a2.w;
        hv[12] = a3.x; hv[13] = a3.y;
#pragma unroll
        for (int i = 0; i < 4; ++i) {
            float a = 0.f;
#pragma unroll
            for (int k = 0; k < 11; ++k) a = fmaf(G[k], hv[i + k], a);
            acc[f][i] = a;
        }
    }

    float local = 0.f;
    const int gc = C0 + c;
#pragma unroll
    for (int i = 0; i < 4; ++i) {
        const int gr = R0 + r0 + i;
        if (gr < H && gc < W) {
            const float mu1 = acc[0][i], mu2 = acc[1][i];
            const float mu1s = mu1 * mu1, mu2s = mu2 * mu2, m12 = mu1 * mu2;
            const float s1  = acc[2][i] - mu1s;
            const float s2  = acc[3][i] - mu2s;
            const float s12 = acc[4][i] - m12;
            const float num = (2.f * m12 + C1) * (2.f * s12 + C2);
            const float den = (mu1s + mu2s + C1) * (s1 + s2 + C2);
            local += num * __builtin_amdgcn_rcpf(den + 1e-8f);
        }
    }

    // ---- reduction: wave shuffle -> LDS -> one atomic per block ----
#pragma unroll
    for (int off = 32; off > 0; off >>= 1) local += __shfl_down(local, off, 64);
    if ((t & 63) == 0) wred[t >> 6] = local;
    __syncthreads();
    if (t == 0) atomicAdd(sum_out, wred[0] + wred[1] + wred[2] + wred[3]);
}

__global__ void finalize_kernel(const float* __restrict__ sums,
                                float* __restrict__ out)
{
    if (threadIdx.x == 0 && blockIdx.x == 0) {
        const float w[5] = {0.0448f, 0.2856f, 0.3001f, 0.2363f, 0.1333f};
        const float wsum = w[0] + w[1] + w[2] + w[3] + w[4];
        float acc = 0.f;
#pragma unroll
        for (int i = 0; i < 5; ++i) {
            const int d = 512 >> i;
            const float cnt = (float)NIMG * (float)d * (float)d;
            acc += (w[i] / wsum) * (sums[i] / cnt);
        }
        out[0] = 1.0f - acc;
    }
}

extern "C" void kernel_launch(void* const* d_in, const int* in_sizes, int n_in,
                              void* d_out, int out_size, void* d_ws, size_t ws_size,
                              hipStream_t stream)
{
    const float* pred = (const float*)d_in[0];
    const float* targ = (const float*)d_in[1];
    float* out = (float*)d_out;
    float* ws  = (float*)d_ws;

    float* sums = ws; // 8 floats (5 used)
    const long n1 = (long)NIMG * 256 * 256;
    const long n2 = (long)NIMG * 128 * 128;
    const long n3 = (long)NIMG * 64 * 64;
    const long n4 = (long)NIMG * 32 * 32;
    float* x1 = ws + 64;
    float* y1 = x1 + n1;
    float* x2 = y1 + n1;
    float* y2 = x2 + n2;
    float* x3 = y2 + n2;
    float* y3 = x3 + n3;
    float* x4 = y3 + n3;
    float* y4 = x4 + n4;

    hipMemsetAsync(sums, 0, 8 * sizeof(float), stream);

    { dim3 g(512 / TW, 512 / TH, NIMG);
      ssim_level_kernel<<<g, 256, 0, stream>>>(pred, targ, x1, y1, sums + 0, 512, 512, 1); }
    { dim3 g(256 / TW, 256 / TH, NIMG);
      ssim_level_kernel<<<g, 256, 0, stream>>>(x1, y1, x2, y2, sums + 1, 256, 256, 1); }
    { dim3 g(128 / TW, 128 / TH, NIMG);
      ssim_level_kernel<<<g, 256, 0, stream>>>(x2, y2, x3, y3, sums + 2, 128, 128, 1); }
    { dim3 g(1, 64 / TH, NIMG);
      ssim_level_kernel<<<g, 256, 0, stream>>>(x3, y3, x4, y4, sums + 3, 64, 64, 1); }
    { dim3 g(1, 32 / TH, NIMG);
      ssim_level_kernel<<<g, 256, 0, stream>>>(x4, y4, nullptr, nullptr, sums + 4, 32, 32, 0); }
    finalize_kernel<<<1, 64, 0, stream>>>(sums, out);
}

// Round 3
// 343.061 us; speedup vs baseline: 1.2638x; 1.2638x over previous
//
#include <hip/hip_runtime.h>

// MS-SSIM loss, 5 levels, fused per-level kernel.
// Tile 64x16, 256 threads, LDS 34.3 KB -> 4 blocks/CU (16 waves).
// h-fields stored ROW-MAJOR pitch 66 (even, not mult-of-4):
//   - phase-H float2 writes: r-major lanes -> banks spread, conflict-free
//   - phase-V scalar b32 column reads: banks = c mod 32, exact 2-way = free
// (transposed b128 reads are structurally >=8-way aliased: any 16B-aligned
//  pitch gives only multiple-of-4 start banks -- rounds 1-2 measured 2.4e7+.)
// Phase H: 8-wide strips, 12 float4 window loads, per-strip fast/slow path.
// Phase V: vertical conv in regs + fused SSIM (v_rcp) + wave reduce + 1 atomic.
// Avg-pool 2x2 fused (1 output/thread, float2 loads).

#define TW 64
#define TH 16
#define HHALO 26            // TH + 10 rows of h-conv
#define HPITCH 66           // 64 + 2: even pitch, odd/2 -> spread banks
#define PLANE (HHALO * HPITCH) // 1716 words per field plane
#define NIMG 48             // 16 * 3

__global__ __launch_bounds__(256, 4) void ssim_level_kernel(
    const float* __restrict__ x, const float* __restrict__ y,
    float* __restrict__ dsx, float* __restrict__ dsy,
    float* __restrict__ sum_out, int H, int W, int do_ds)
{
    const float G[11] = {
        0.00102839f, 0.00759877f, 0.03600077f, 0.10936069f, 0.21300539f,
        0.26601173f, 0.21300539f, 0.10936069f, 0.03600077f, 0.00759877f,
        0.00102839f};
    const float C1 = 4.0e-4f;
    const float C2 = 3.6e-3f;

    __shared__ __align__(16) float hfT[5 * PLANE]; // 34,320 B
    __shared__ float wred[4];

    const int t   = threadIdx.x;
    const int img = blockIdx.z;
    const int C0  = blockIdx.x * TW;
    const int R0  = blockIdx.y * TH;
    const long base = (long)img * H * W;

    // ---- fused avg-pool 2x2 for next level: one output per thread ----
    if (do_ds) {
        const int dsW = W >> 1, dsH = H >> 1;
        const long dbase = (long)img * dsH * dsW;
        const int dr = t >> 5;       // 0..7
        const int dc = t & 31;       // 0..31
        const int gr2 = (R0 >> 1) + dr;
        const int gc2 = (C0 >> 1) + dc;
        if (gr2 < dsH && gc2 < dsW) {
            const long src = base + (long)(2 * gr2) * W + 2 * gc2;
            const float2 a0 = *reinterpret_cast<const float2*>(x + src);
            const float2 a1 = *reinterpret_cast<const float2*>(x + src + W);
            const float2 b0 = *reinterpret_cast<const float2*>(y + src);
            const float2 b1 = *reinterpret_cast<const float2*>(y + src + W);
            dsx[dbase + (long)gr2 * dsW + gc2] = 0.25f * (a0.x + a0.y + a1.x + a1.y);
            dsy[dbase + (long)gr2 * dsW + gc2] = 0.25f * (b0.x + b0.y + b1.x + b1.y);
        }
    }

    // ---- Phase H: 26 rows x 8 col-octets = 208 strips, one pass, r-major ----
    if (t < HHALO * (TW / 8)) {
        const int r  = t % HHALO;        // consecutive lanes -> consecutive r
        const int q  = t / HHALO;
        const int gr = R0 + r - 5;
        const bool rok = ((unsigned)gr < (unsigned)H);
        const int gc0 = C0 + (q << 3) - 8;   // window start (16B aligned)

        // window indices used by the conv: 3..20 (out col j tap k -> j+k+3)
        float xv[24], yv[24];
        const bool fast = rok && (gc0 >= 0) && (gc0 + 24 <= W);
        if (fast) {
            const float* px = x + base + (long)gr * W + gc0;
            const float* py = y + base + (long)gr * W + gc0;
#pragma unroll
            for (int v = 0; v < 6; ++v) {
                const float4 a = reinterpret_cast<const float4*>(px)[v];
                const float4 b = reinterpret_cast<const float4*>(py)[v];
                xv[4 * v + 0] = a.x; xv[4 * v + 1] = a.y;
                xv[4 * v + 2] = a.z; xv[4 * v + 3] = a.w;
                yv[4 * v + 0] = b.x; yv[4 * v + 1] = b.y;
                yv[4 * v + 2] = b.z; yv[4 * v + 3] = b.w;
            }
        } else {
            const float* xrow = x + base + (long)gr * W;
            const float* yrow = y + base + (long)gr * W;
#pragma unroll
            for (int k = 3; k < 21; ++k) {
                const int gc = gc0 + k;
                const bool ok = rok && ((unsigned)gc < (unsigned)W);
                xv[k] = ok ? xrow[gc] : 0.0f;
                yv[k] = ok ? yrow[gc] : 0.0f;
            }
        }

        float xx[18], yy[18], xy[18];
#pragma unroll
        for (int k = 0; k < 18; ++k) {
            const float a = xv[k + 3], b = yv[k + 3];
            xx[k] = a * a; yy[k] = b * b; xy[k] = a * b;
        }

        // 8 outputs; pack into float2 pairs for aligned b64 LDS writes
        float hx[8], hy[8], hxx[8], hyy[8], hxy[8];
#pragma unroll
        for (int j = 0; j < 8; ++j) {
            float sx = 0.f, sy = 0.f, sxx = 0.f, syy = 0.f, sxy = 0.f;
#pragma unroll
            for (int k = 0; k < 11; ++k) {
                const float g = G[k];
                sx  = fmaf(g, xv[j + k + 3], sx);
                sy  = fmaf(g, yv[j + k + 3], sy);
                sxx = fmaf(g, xx[j + k], sxx);
                syy = fmaf(g, yy[j + k], syy);
                sxy = fmaf(g, xy[j + k], sxy);
            }
            hx[j] = sx; hy[j] = sy; hxx[j] = sxx; hyy[j] = syy; hxy[j] = sxy;
        }
        float* hp = &hfT[r * HPITCH + (q << 3)];   // even word offset: b64 ok
#pragma unroll
        for (int p = 0; p < 4; ++p) {
            reinterpret_cast<float2*>(hp + 0 * PLANE)[p] = make_float2(hx[2*p],  hx[2*p+1]);
            reinterpret_cast<float2*>(hp + 1 * PLANE)[p] = make_float2(hy[2*p],  hy[2*p+1]);
            reinterpret_cast<float2*>(hp + 2 * PLANE)[p] = make_float2(hxx[2*p], hxx[2*p+1]);
            reinterpret_cast<float2*>(hp + 3 * PLANE)[p] = make_float2(hyy[2*p], hyy[2*p+1]);
            reinterpret_cast<float2*>(hp + 4 * PLANE)[p] = make_float2(hxy[2*p], hxy[2*p+1]);
        }
    }
    __syncthreads();

    // ---- Phase V: thread = (col, 4-row strip); scalar b32 column reads ----
    const int c   = t & 63;
    const int rr0 = (t >> 6) << 2;      // 0,4,8,12
    float acc[5][4];
#pragma unroll
    for (int f = 0; f < 5; ++f) {
        const float* hp = &hfT[f * PLANE + rr0 * HPITCH + c];
        float hv[14];
#pragma unroll
        for (int k = 0; k < 14; ++k) hv[k] = hp[k * HPITCH];
#pragma unroll
        for (int i = 0; i < 4; ++i) {
            float a = 0.f;
#pragma unroll
            for (int k = 0; k < 11; ++k) a = fmaf(G[k], hv[i + k], a);
            acc[f][i] = a;
        }
    }

    float local = 0.f;
    const int gc = C0 + c;
#pragma unroll
    for (int i = 0; i < 4; ++i) {
        const int gr = R0 + rr0 + i;
        if (gr < H && gc < W) {
            const float mu1 = acc[0][i], mu2 = acc[1][i];
            const float mu1s = mu1 * mu1, mu2s = mu2 * mu2, m12 = mu1 * mu2;
            const float s1  = acc[2][i] - mu1s;
            const float s2  = acc[3][i] - mu2s;
            const float s12 = acc[4][i] - m12;
            const float num = (2.f * m12 + C1) * (2.f * s12 + C2);
            const float den = (mu1s + mu2s + C1) * (s1 + s2 + C2);
            local += num * __builtin_amdgcn_rcpf(den + 1e-8f);
        }
    }

    // ---- reduction: wave shuffle -> LDS -> one atomic per block ----
#pragma unroll
    for (int off = 32; off > 0; off >>= 1) local += __shfl_down(local, off, 64);
    if ((t & 63) == 0) wred[t >> 6] = local;
    __syncthreads();
    if (t == 0) atomicAdd(sum_out, wred[0] + wred[1] + wred[2] + wred[3]);
}

__global__ void finalize_kernel(const float* __restrict__ sums,
                                float* __restrict__ out)
{
    if (threadIdx.x == 0 && blockIdx.x == 0) {
        const float w[5] = {0.0448f, 0.2856f, 0.3001f, 0.2363f, 0.1333f};
        const float wsum = w[0] + w[1] + w[2] + w[3] + w[4];
        float acc = 0.f;
#pragma unroll
        for (int i = 0; i < 5; ++i) {
            const int d = 512 >> i;
            const float cnt = (float)NIMG * (float)d * (float)d;
            acc += (w[i] / wsum) * (sums[i] / cnt);
        }
        out[0] = 1.0f - acc;
    }
}

extern "C" void kernel_launch(void* const* d_in, const int* in_sizes, int n_in,
                              void* d_out, int out_size, void* d_ws, size_t ws_size,
                              hipStream_t stream)
{
    const float* pred = (const float*)d_in[0];
    const float* targ = (const float*)d_in[1];
    float* out = (float*)d_out;
    float* ws  = (float*)d_ws;

    float* sums = ws; // 8 floats (5 used)
    const long n1 = (long)NIMG * 256 * 256;
    const long n2 = (long)NIMG * 128 * 128;
    const long n3 = (long)NIMG * 64 * 64;
    const long n4 = (long)NIMG * 32 * 32;
    float* x1 = ws + 64;
    float* y1 = x1 + n1;
    float* x2 = y1 + n1;
    float* y2 = x2 + n2;
    float* x3 = y2 + n2;
    float* y3 = x3 + n3;
    float* x4 = y3 + n3;
    float* y4 = x4 + n4;

    hipMemsetAsync(sums, 0, 8 * sizeof(float), stream);

    { dim3 g(512 / TW, 512 / TH, NIMG);
      ssim_level_kernel<<<g, 256, 0, stream>>>(pred, targ, x1, y1, sums + 0, 512, 512, 1); }
    { dim3 g(256 / TW, 256 / TH, NIMG);
      ssim_level_kernel<<<g, 256, 0, stream>>>(x1, y1, x2, y2, sums + 1, 256, 256, 1); }
    { dim3 g(128 / TW, 128 / TH, NIMG);
      ssim_level_kernel<<<g, 256, 0, stream>>>(x2, y2, x3, y3, sums + 2, 128, 128, 1); }
    { dim3 g(1, 64 / TH, NIMG);
      ssim_level_kernel<<<g, 256, 0, stream>>>(x3, y3, x4, y4, sums + 3, 64, 64, 1); }
    { dim3 g(1, 32 / TH, NIMG);
      ssim_level_kernel<<<g, 256, 0, stream>>>(x4, y4, nullptr, nullptr, sums + 4, 32, 32, 0); }
    finalize_kernel<<<1, 64, 0, stream>>>(sums, out);
}